// Round 7
// baseline (259.418 us; speedup 1.0000x reference)
//
#include <hip/hip_runtime.h>
#include <hip/hip_bf16.h>

// B=64, T=128, D=512. gates = x @ w_ih^T per t; f-gate unused (c0=0).
// K0: split x fp32 -> interleaved bf16 hi/lo groups in d_ws.
// K1: barrier-free, LDS-free MFMA GEMM. One wave = 16 b-rows x 16 d-cols x 3
//     gates (acc only 12 VGPR). w loaded direct from global (fp32, cvt in
//     regs), x hi/lo frags from ws. Full K unroll; 4 blocks/CU = 16
//     independent waves/CU -> smooth deep memory request flow.
// K2: in-place softmax(20*h).

#define B_ 64
#define T_ 128
#define D_ 512

typedef float f32x4_t __attribute__((ext_vector_type(4)));
typedef __bf16 bf16x8_t __attribute__((ext_vector_type(8)));
typedef unsigned short u16x8_t __attribute__((ext_vector_type(8)));

// Round-to-nearest split: f = hi + lo + O(2^-18 |f|).
__device__ __forceinline__ void cvt8(float4 a, float4 b, u16x8_t& hi, u16x8_t& lo) {
  float f[8] = {a.x, a.y, a.z, a.w, b.x, b.y, b.z, b.w};
#pragma unroll
  for (int j = 0; j < 8; ++j) {
    __bf16 h = (__bf16)f[j];
    hi[j] = __builtin_bit_cast(unsigned short, h);
    float r = f[j] - (float)h;
    __bf16 l = (__bf16)r;
    lo[j] = __builtin_bit_cast(unsigned short, l);
  }
}

__device__ __forceinline__ f32x4_t mfma16(u16x8_t a, u16x8_t b, f32x4_t c) {
  return __builtin_amdgcn_mfma_f32_16x16x32_bf16(
      __builtin_bit_cast(bf16x8_t, a), __builtin_bit_cast(bf16x8_t, b), c, 0, 0, 0);
}

__device__ __forceinline__ float sigmoid_f(float v) { return 1.0f / (1.0f + __expf(-v)); }
__device__ __forceinline__ float tanh_f(float v) { return 1.0f - 2.0f / (__expf(2.0f * v) + 1.0f); }

// K0: one 8-elem group per thread. ws group j: ushorts [j*16,+8)=hi, [+8,+16)=lo.
__global__ __launch_bounds__(256) void split_x_kernel(const float* __restrict__ x,
                                                      unsigned short* __restrict__ ws) {
  const int j = blockIdx.x * 256 + threadIdx.x;
  float4 a = *(const float4*)(x + (size_t)j * 8);
  float4 b = *(const float4*)(x + (size_t)j * 8 + 4);
  u16x8_t hi, lo;
  cvt8(a, b, hi, lo);
  *(u16x8_t*)(ws + (size_t)j * 16) = hi;
  *(u16x8_t*)(ws + (size_t)j * 16 + 8) = lo;
}

// Grid 4096 = 128 t x 32 col-groups. Block 256 = 4 waves; wave wv owns
// b-rows [wv*16,+16), cols [cg*16,+16), all 3 gates. No LDS, no barriers.
__global__ __launch_bounds__(256, 4) void lstm_gates_kernel(
    const unsigned short* __restrict__ xs, const float* __restrict__ w,
    float* __restrict__ out) {
  const int lane = threadIdx.x & 63;
  const int wv = threadIdx.x >> 6;
  const int bid = blockIdx.x;
  // XCD swizzle (bijective: 4096 % 8 == 0): each XCD owns 16 consecutive t's,
  // so x[t] slices are fetched once per XCD L2 and w streams are t-local.
  const int work = (bid & 7) * 512 + (bid >> 3);
  const int t = work >> 5;
  const int cg = work & 31;

  const int c = lane & 15;   // A-row / B-col within 16x16 tile
  const int kg = lane >> 4;  // k-subgroup: floats kg*8..+8 of each K=32 chunk

  // x hi/lo groups: row (b*T+t) has 64 groups of 16 ushorts; iter s needs
  // group 4s+kg -> ushort offset s*64 + kg*16.
  const unsigned short* xp = xs + ((size_t)((wv * 16 + c) * T_ + t) << 10) + kg * 16;

  // w[t][row][k] fp32: rows i(0), g(1024), o(1536) + col; f rows skipped.
  const int col = cg * 16 + c;
  const char* wt = (const char*)w + ((size_t)t << 22);
  const char* wp0 = wt + (size_t)(0 + col) * 2048 + kg * 32;
  const char* wp1 = wt + (size_t)(1024 + col) * 2048 + kg * 32;
  const char* wp2 = wt + (size_t)(1536 + col) * 2048 + kg * 32;

  f32x4_t acc0 = {0.f, 0.f, 0.f, 0.f};
  f32x4_t acc1 = {0.f, 0.f, 0.f, 0.f};
  f32x4_t acc2 = {0.f, 0.f, 0.f, 0.f};

#pragma unroll
  for (int s = 0; s < 16; ++s) {  // K = 16 chunks of 32
    u16x8_t xh = *(const u16x8_t*)(xp + s * 64);
    u16x8_t xl = *(const u16x8_t*)(xp + s * 64 + 8);

    float4 a0 = *(const float4*)(wp0 + s * 128);
    float4 b0 = *(const float4*)(wp0 + s * 128 + 16);
    float4 a1 = *(const float4*)(wp1 + s * 128);
    float4 b1 = *(const float4*)(wp1 + s * 128 + 16);
    float4 a2 = *(const float4*)(wp2 + s * 128);
    float4 b2 = *(const float4*)(wp2 + s * 128 + 16);

    u16x8_t wh, wl;
    cvt8(a0, b0, wh, wl);
    acc0 = mfma16(xh, wh, acc0);
    acc0 = mfma16(xh, wl, acc0);
    acc0 = mfma16(xl, wh, acc0);
    cvt8(a1, b1, wh, wl);
    acc1 = mfma16(xh, wh, acc1);
    acc1 = mfma16(xh, wl, acc1);
    acc1 = mfma16(xl, wh, acc1);
    cvt8(a2, b2, wh, wl);
    acc2 = mfma16(xh, wh, acc2);
    acc2 = mfma16(xh, wl, acc2);
    acc2 = mfma16(xl, wh, acc2);
  }

  // C frag: col = c, row = kg*4 + j. LSTM activation + h store.
#pragma unroll
  for (int j = 0; j < 4; ++j) {
    float iv = acc0[j];
    float gv = acc1[j];
    float ov = acc2[j];
    float cc = sigmoid_f(iv) * tanh_f(gv);
    float h = sigmoid_f(ov) * tanh_f(cc);
    int b = wv * 16 + kg * 4 + j;
    out[(((size_t)b * T_ + t) << 9) + col] = h;
  }
}

// One wave per (b,t) row of 512; in-place softmax(20*h).
__global__ __launch_bounds__(256) void softmax_kernel(float* __restrict__ io) {
  const int lane = threadIdx.x & 63;
  const int row = blockIdx.x * 4 + (threadIdx.x >> 6);
  float* p = io + ((size_t)row << 9);
  float4 v0 = *(const float4*)(p + lane * 4);
  float4 v1 = *(const float4*)(p + 256 + lane * 4);
  float l[8] = {20.f * v0.x, 20.f * v0.y, 20.f * v0.z, 20.f * v0.w,
                20.f * v1.x, 20.f * v1.y, 20.f * v1.z, 20.f * v1.w};
  float m = l[0];
#pragma unroll
  for (int j = 1; j < 8; ++j) m = fmaxf(m, l[j]);
#pragma unroll
  for (int o = 32; o > 0; o >>= 1) m = fmaxf(m, __shfl_xor(m, o, 64));
  float e[8], s = 0.f;
#pragma unroll
  for (int j = 0; j < 8; ++j) {
    e[j] = __expf(l[j] - m);
    s += e[j];
  }
#pragma unroll
  for (int o = 32; o > 0; o >>= 1) s += __shfl_xor(s, o, 64);
  float inv = 1.0f / s;
  float4 o0 = {e[0] * inv, e[1] * inv, e[2] * inv, e[3] * inv};
  float4 o1 = {e[4] * inv, e[5] * inv, e[6] * inv, e[7] * inv};
  *(float4*)(p + lane * 4) = o0;
  *(float4*)(p + 256 + lane * 4) = o1;
}

extern "C" void kernel_launch(void* const* d_in, const int* in_sizes, int n_in,
                              void* d_out, int out_size, void* d_ws, size_t ws_size,
                              hipStream_t stream) {
  const float* x = (const float*)d_in[0];
  const float* w = (const float*)d_in[1];
  float* out = (float*)d_out;
  unsigned short* xs = (unsigned short*)d_ws;  // 33.6 MB bf16 hi/lo groups

  split_x_kernel<<<(B_ * T_ * D_) / (256 * 8), 256, 0, stream>>>(x, xs);
  lstm_gates_kernel<<<T_ * 32, 256, 0, stream>>>(xs, w, out);
  softmax_kernel<<<(B_ * T_) / 4, 256, 0, stream>>>(out);
}

// Round 8
// 220.405 us; speedup vs baseline: 1.1770x; 1.1770x over previous
//
#include <hip/hip_runtime.h>
#include <hip/hip_bf16.h>

// B=64, T=128, D=512. gates = x @ w_ih^T per t; f-gate unused (c0=0).
// K0: split x fp32 -> interleaved bf16 hi/lo groups in d_ws.
// K1: wave-independent staged GEMM. Block = 1 wave = (t, 16 cols) x all 64
//     b-rows x 3 gates. Private 2x4KB LDS; each substage (gate g, K-eighth kq)
//     DMAs 16 w-rows x 256B (sequential per row) via global_load_lds,
//     depth-1 prefetch, counted vmcnt(4). ZERO s_barriers -> ~12 independent
//     DMA streams per CU. bf16x3 MFMA; LSTM activation fused.
// K2: in-place softmax(20*h).

#define B_ 64
#define T_ 128
#define D_ 512

typedef float f32x4_t __attribute__((ext_vector_type(4)));
typedef __bf16 bf16x8_t __attribute__((ext_vector_type(8)));
typedef unsigned short u16x8_t __attribute__((ext_vector_type(8)));
typedef unsigned int u32;
typedef const __attribute__((address_space(1))) u32* gp_t;
typedef __attribute__((address_space(3))) u32* lp_t;

#define GLOAD_LDS16(g, l) \
  __builtin_amdgcn_global_load_lds((gp_t)(const void*)(g), (lp_t)(void*)(l), 16, 0, 0)

// Round-to-nearest split: f = hi + lo + O(2^-18 |f|).
__device__ __forceinline__ void cvt8(float4 a, float4 b, u16x8_t& hi, u16x8_t& lo) {
  float f[8] = {a.x, a.y, a.z, a.w, b.x, b.y, b.z, b.w};
#pragma unroll
  for (int j = 0; j < 8; ++j) {
    __bf16 h = (__bf16)f[j];
    hi[j] = __builtin_bit_cast(unsigned short, h);
    float r = f[j] - (float)h;
    __bf16 l = (__bf16)r;
    lo[j] = __builtin_bit_cast(unsigned short, l);
  }
}

__device__ __forceinline__ f32x4_t mfma16(u16x8_t a, u16x8_t b, f32x4_t c) {
  return __builtin_amdgcn_mfma_f32_16x16x32_bf16(
      __builtin_bit_cast(bf16x8_t, a), __builtin_bit_cast(bf16x8_t, b), c, 0, 0, 0);
}

__device__ __forceinline__ float sigmoid_f(float v) { return 1.0f / (1.0f + __expf(-v)); }
__device__ __forceinline__ float tanh_f(float v) { return 1.0f - 2.0f / (__expf(2.0f * v) + 1.0f); }

// K0: one 8-elem group per thread. ws group j: ushorts [j*16,+8)=hi, [+8,+16)=lo.
__global__ __launch_bounds__(256) void split_x_kernel(const float* __restrict__ x,
                                                      unsigned short* __restrict__ ws) {
  const int j = blockIdx.x * 256 + threadIdx.x;
  float4 a = *(const float4*)(x + (size_t)j * 8);
  float4 b = *(const float4*)(x + (size_t)j * 8 + 4);
  u16x8_t hi, lo;
  cvt8(a, b, hi, lo);
  *(u16x8_t*)(ws + (size_t)j * 16) = hi;
  *(u16x8_t*)(ws + (size_t)j * 16 + 8) = lo;
}

// Grid 4096 = 128 t x 32 col-groups; 64 threads (1 wave).
__global__ __launch_bounds__(64, 3) void lstm_gates_kernel(
    const unsigned short* __restrict__ xs, const float* __restrict__ w,
    float* __restrict__ out) {
  __shared__ float lds[2][1024];  // 2 x 4KB, wave-private (XOR-swizzled rows)
  const int lane = threadIdx.x;
  const int bid = blockIdx.x;
  // XCD swizzle (bijective, 4096%8==0): each XCD owns 16 consecutive t's.
  const int work = (bid & 7) * 512 + (bid >> 3);
  const int t = work >> 5;
  const int cg = work & 31;

  const int c = lane & 15;   // A-row / B-col within 16x16 tile
  const int kg = lane >> 4;  // k-subgroup 0..3

  // x hi/lo group rows for the 4 b-row groups (64 groups of 16 ushorts per row).
  const unsigned short* xp[4];
#pragma unroll
  for (int bg = 0; bg < 4; ++bg)
    xp[bg] = xs + ((size_t)((bg * 16 + c) * T_ + t) << 10);

  // DMA per-lane source offsets. Inst i covers rows i*4..i*4+3 (row = i*4+lane/16),
  // 256B per row; source pre-swizzled so linear LDS dst holds swizzled content:
  // content(P) = linear(P ^ ((row(P)&7)<<4)), row(P)=P>>8.
  unsigned dsrc[4];
#pragma unroll
  for (int i = 0; i < 4; ++i) {
    int row = i * 4 + (lane >> 4);
    dsrc[i] = (unsigned)(row * 2048) +
              ((unsigned)((lane & 15) * 16) ^ (unsigned)((row & 7) << 4));
  }

  const int grow[3] = {0, 1024, 1536};  // gate row bases: i, g(2D), o(3D); f skipped
  const char* wt = (const char*)w + ((size_t)t << 22) + (size_t)(cg * 16) * 2048;

#define DMA_STAGE(G, KQ, BUF)                                      \
  do {                                                             \
    const char* gb_ = wt + (size_t)grow[G] * 2048 + (KQ) * 256;    \
    char* lb_ = (char*)&lds[BUF][0];                               \
    GLOAD_LDS16(gb_ + dsrc[0], lb_ + 0);                           \
    GLOAD_LDS16(gb_ + dsrc[1], lb_ + 1024);                        \
    GLOAD_LDS16(gb_ + dsrc[2], lb_ + 2048);                        \
    GLOAD_LDS16(gb_ + dsrc[3], lb_ + 3072);                        \
  } while (0)

  f32x4_t acc[4][3];
#pragma unroll
  for (int bg = 0; bg < 4; ++bg)
#pragma unroll
    for (int g = 0; g < 3; ++g) acc[bg][g] = (f32x4_t){0.f, 0.f, 0.f, 0.f};

  DMA_STAGE(0, 0, 0);  // prologue

  const unsigned sw = (unsigned)((c & 7) << 4);

#pragma unroll
  for (int s = 0; s < 24; ++s) {  // substage: gate g = s>>3, K-eighth kq = s&7
    const int g = s >> 3, kq = s & 7;
    const int buf = s & 1;

    // x(s) frags FIRST (older than next DMA -> covered by vmcnt(4)).
    u16x8_t xh[4][2], xl[4][2];
#pragma unroll
    for (int st = 0; st < 2; ++st) {
      const int goff = (kq * 8 + st * 4 + kg) * 16;
#pragma unroll
      for (int bg = 0; bg < 4; ++bg) {
        xh[bg][st] = *(const u16x8_t*)(xp[bg] + goff);
        xl[bg][st] = *(const u16x8_t*)(xp[bg] + goff + 8);
      }
    }
    __builtin_amdgcn_sched_barrier(0);
    if (s + 1 < 24) DMA_STAGE((s + 1) >> 3, (s + 1) & 7, (s + 1) & 1);
    __builtin_amdgcn_sched_barrier(0);
    if (s + 1 < 24) asm volatile("s_waitcnt vmcnt(4)" ::: "memory");  // dma(s)+x(s) done
    else            asm volatile("s_waitcnt vmcnt(0)" ::: "memory");
    __builtin_amdgcn_sched_barrier(0);

    const char* lb = (const char*)&lds[buf][0];
#pragma unroll
    for (int st = 0; st < 2; ++st) {
      const unsigned lin = (unsigned)(c * 256 + st * 128 + kg * 32);
      float4 wa = *(const float4*)(lb + (lin ^ sw));
      float4 wb = *(const float4*)(lb + ((lin + 16) ^ sw));
      u16x8_t wh, wl;
      cvt8(wa, wb, wh, wl);
#pragma unroll
      for (int bg = 0; bg < 4; ++bg) {
        acc[bg][g] = mfma16(xh[bg][st], wh, acc[bg][g]);
        acc[bg][g] = mfma16(xh[bg][st], wl, acc[bg][g]);
        acc[bg][g] = mfma16(xl[bg][st], wh, acc[bg][g]);
      }
    }
  }
#undef DMA_STAGE

  // LSTM activation + h write. C frag: col = c, row = kg*4 + j.
#pragma unroll
  for (int bg = 0; bg < 4; ++bg) {
#pragma unroll
    for (int j = 0; j < 4; ++j) {
      float iv = acc[bg][0][j];
      float gv = acc[bg][1][j];
      float ov = acc[bg][2][j];
      float cc = sigmoid_f(iv) * tanh_f(gv);
      float h = sigmoid_f(ov) * tanh_f(cc);
      int b = bg * 16 + kg * 4 + j;
      out[(((size_t)b * T_ + t) << 9) + cg * 16 + c] = h;
    }
  }
}

// One wave per (b,t) row of 512; in-place softmax(20*h).
__global__ __launch_bounds__(256) void softmax_kernel(float* __restrict__ io) {
  const int lane = threadIdx.x & 63;
  const int row = blockIdx.x * 4 + (threadIdx.x >> 6);
  float* p = io + ((size_t)row << 9);
  float4 v0 = *(const float4*)(p + lane * 4);
  float4 v1 = *(const float4*)(p + 256 + lane * 4);
  float l[8] = {20.f * v0.x, 20.f * v0.y, 20.f * v0.z, 20.f * v0.w,
                20.f * v1.x, 20.f * v1.y, 20.f * v1.z, 20.f * v1.w};
  float m = l[0];
#pragma unroll
  for (int j = 1; j < 8; ++j) m = fmaxf(m, l[j]);
#pragma unroll
  for (int o = 32; o > 0; o >>= 1) m = fmaxf(m, __shfl_xor(m, o, 64));
  float e[8], s = 0.f;
#pragma unroll
  for (int j = 0; j < 8; ++j) {
    e[j] = __expf(l[j] - m);
    s += e[j];
  }
#pragma unroll
  for (int o = 32; o > 0; o >>= 1) s += __shfl_xor(s, o, 64);
  float inv = 1.0f / s;
  float4 o0 = {e[0] * inv, e[1] * inv, e[2] * inv, e[3] * inv};
  float4 o1 = {e[4] * inv, e[5] * inv, e[6] * inv, e[7] * inv};
  *(float4*)(p + lane * 4) = o0;
  *(float4*)(p + 256 + lane * 4) = o1;
}

extern "C" void kernel_launch(void* const* d_in, const int* in_sizes, int n_in,
                              void* d_out, int out_size, void* d_ws, size_t ws_size,
                              hipStream_t stream) {
  const float* x = (const float*)d_in[0];
  const float* w = (const float*)d_in[1];
  float* out = (float*)d_out;
  unsigned short* xs = (unsigned short*)d_ws;  // 33.6 MB bf16 hi/lo groups

  split_x_kernel<<<(B_ * T_ * D_) / (256 * 8), 256, 0, stream>>>(x, xs);
  lstm_gates_kernel<<<T_ * 32, 64, 0, stream>>>(xs, w, out);
  softmax_kernel<<<(B_ * T_) / 4, 256, 0, stream>>>(out);
}

// Round 9
// 98.372 us; speedup vs baseline: 2.6371x; 2.2405x over previous
//
#include <hip/hip_runtime.h>
#include <hip/hip_bf16.h>

// B=64, T=128, D=512. gates = x @ w_ih^T per t; f-gate unused (c0=0).
// K1: per-(t, 64-col) block, 4 waves. x rows -> bf16 hi/lo frags in VGPRs
//     (64 regs per K-half phase). 24 substages (2 K-halves x 3 gates x 4
//     col-groups): REG-STAGED w: 4x global_load_dwordx4 (1KB sequential per
//     inst) -> cvt to bf16 hi/lo -> swizzled ds_write into 2x16KB dbuf LDS.
//     Loads issued 2 substages ahead (pure data-dep waits, no manual vmcnt);
//     ONE barrier per substage. Compute phase: ds_read_b128 of ready bf16
//     frags + MFMA only (no VALU). LSTM activation fused; h -> d_out.
// K2: in-place softmax(20*h).

#define B_ 64
#define T_ 128
#define D_ 512

typedef float f32x4_t __attribute__((ext_vector_type(4)));
typedef __bf16 bf16x8_t __attribute__((ext_vector_type(8)));
typedef unsigned short u16x8_t __attribute__((ext_vector_type(8)));
typedef unsigned short u16x4_t __attribute__((ext_vector_type(4)));

#define SWZ(r) ((unsigned)(((r) & 7) << 4))

// Round-to-nearest split: f = hi + lo + O(2^-18 |f|).
__device__ __forceinline__ void cvt8(float4 a, float4 b, u16x8_t& hi, u16x8_t& lo) {
  float f[8] = {a.x, a.y, a.z, a.w, b.x, b.y, b.z, b.w};
#pragma unroll
  for (int j = 0; j < 8; ++j) {
    __bf16 h = (__bf16)f[j];
    hi[j] = __builtin_bit_cast(unsigned short, h);
    float r = f[j] - (float)h;
    lo[j] = __builtin_bit_cast(unsigned short, (__bf16)r);
  }
}

__device__ __forceinline__ void cvt4(float4 v, u16x4_t& hi, u16x4_t& lo) {
  float f[4] = {v.x, v.y, v.z, v.w};
#pragma unroll
  for (int j = 0; j < 4; ++j) {
    __bf16 h = (__bf16)f[j];
    hi[j] = __builtin_bit_cast(unsigned short, h);
    float r = f[j] - (float)h;
    lo[j] = __builtin_bit_cast(unsigned short, (__bf16)r);
  }
}

__device__ __forceinline__ f32x4_t mfma16(u16x8_t a, u16x8_t b, f32x4_t c) {
  return __builtin_amdgcn_mfma_f32_16x16x32_bf16(
      __builtin_bit_cast(bf16x8_t, a), __builtin_bit_cast(bf16x8_t, b), c, 0, 0, 0);
}

__device__ __forceinline__ float sigmoid_f(float v) { return 1.0f / (1.0f + __expf(-v)); }
__device__ __forceinline__ float tanh_f(float v) { return 1.0f - 2.0f / (__expf(2.0f * v) + 1.0f); }

// Grid 1024 = 128 t x 8 d-tiles. Wave wv stages rows wv*4..+4, computes b-rows wv*16..+16.
__global__ __launch_bounds__(256, 2) void lstm_gates_kernel(
    const float* __restrict__ x, const float* __restrict__ w, float* __restrict__ out) {
  __shared__ char lds[2][16384];  // 16 rows x 1024B (256 hi-bf16 + 256 lo-bf16 per row)
  const int lane = threadIdx.x & 63;
  const int wv = threadIdx.x >> 6;
  const int bid = blockIdx.x;
  // XCD swizzle: 8 d-tiles of one t share an XCD -> x[t] L2-resident.
  const int work = (bid & 7) * 128 + (bid >> 3);
  const int t = work >> 3;
  const int d0 = (work & 7) << 6;

  const int c = lane & 15;   // frag row/col index
  const int kg = lane >> 4;  // k-subgroup 0..3

  // LDS row layout (1024B): [st 0..7][hi 64B | lo 64B]... linear = st*128 + part*64
  // + kgx*16 + e2, physically XOR'd by SWZ(row). Write side (lane -> its float4):
  const int kl = lane * 4;  // float index within 256-float K-half
  const unsigned wst = (unsigned)(((kl >> 5) & 7) * 128);
  const unsigned wlow = (unsigned)((((kl >> 3) & 3) * 16) + ((kl & 4) << 1));
  unsigned wa_hi[4], wa_lo[4];
#pragma unroll
  for (int i = 0; i < 4; ++i) {
    const int rl = wv * 4 + i;
    wa_hi[i] = (unsigned)(rl * 1024) + wst + (wlow ^ SWZ(rl));
    wa_lo[i] = (unsigned)(rl * 1024) + wst + ((wlow + 64) ^ SWZ(rl));
  }
  // Read side: col c, k-step st, group kg.
  const unsigned q_hi = ((unsigned)(kg * 16)) ^ SWZ(c);
  const unsigned q_lo = ((unsigned)(kg * 16 + 64)) ^ SWZ(c);
  const unsigned rbase = (unsigned)(c * 1024);

  const int grow[3] = {0, 1024, 1536};  // gate row bases i, g(2D), o(3D); f skipped
  const char* wt = (const char*)w + ((size_t)t << 22) + (size_t)d0 * 2048;

  f32x4_t acc[12];
#pragma unroll
  for (int s = 0; s < 12; ++s) acc[s] = (f32x4_t){0.f, 0.f, 0.f, 0.f};

  u16x8_t xh[8], xl[8];
  float4 rs0[4], rs1[4];

  // x frags for K-half KH: b-row wv*16+c, k = KH*256 + st*32 + kg*8 + j.
#define LOADX(KH)                                                                      \
  do {                                                                                 \
    const float* xr_ = x + (((size_t)(wv * 16 + c) * T_ + t) << 9) + (KH) * 256 + kg * 8; \
    _Pragma("unroll") for (int st_ = 0; st_ < 8; ++st_) {                              \
      float4 a_ = *(const float4*)(xr_ + st_ * 32);                                    \
      float4 b_ = *(const float4*)(xr_ + st_ * 32 + 4);                                \
      cvt8(a_, b_, xh[st_], xl[st_]);                                                  \
    }                                                                                  \
  } while (0)

  // substage SS = KH*12 + (g*4+cg): rows grow[g]+cg*16+wv*4..+4, K-half KH.
#define WOFF(SS)                                                                        \
  ((size_t)(grow[((SS) % 12) >> 2] + (((SS) % 12) & 3) * 16 + wv * 4) * 2048 +          \
   (size_t)((SS) / 12) * 1024)

#define ISSUE(SS, RS)                                                                   \
  do {                                                                                  \
    const char* gb_ = wt + WOFF(SS) + lane * 16;                                        \
    _Pragma("unroll") for (int i_ = 0; i_ < 4; ++i_)                                    \
        RS[i_] = *(const float4*)(gb_ + (size_t)i_ * 2048);                             \
  } while (0)

#define WRITE(SS, RS)                                                                   \
  do {                                                                                  \
    char* lb_ = &lds[(SS) & 1][0];                                                      \
    _Pragma("unroll") for (int i_ = 0; i_ < 4; ++i_) {                                  \
      u16x4_t h_, l_;                                                                   \
      cvt4(RS[i_], h_, l_);                                                             \
      *(u16x4_t*)(lb_ + wa_hi[i_]) = h_;                                                \
      *(u16x4_t*)(lb_ + wa_lo[i_]) = l_;                                                \
    }                                                                                   \
  } while (0)

#define BARRIER asm volatile("s_waitcnt lgkmcnt(0)\n\ts_barrier" ::: "memory")

#define COMPUTE(SS)                                                                     \
  do {                                                                                  \
    const char* lb_ = &lds[(SS) & 1][0];                                                \
    _Pragma("unroll") for (int st_ = 0; st_ < 8; ++st_) {                               \
      u16x8_t wh_ = *(const u16x8_t*)(lb_ + rbase + st_ * 128 + q_hi);                  \
      u16x8_t wl_ = *(const u16x8_t*)(lb_ + rbase + st_ * 128 + q_lo);                  \
      acc[(SS) % 12] = mfma16(xh[st_], wh_, acc[(SS) % 12]);                            \
      acc[(SS) % 12] = mfma16(xh[st_], wl_, acc[(SS) % 12]);                            \
      acc[(SS) % 12] = mfma16(xl[st_], wh_, acc[(SS) % 12]);                            \
    }                                                                                   \
  } while (0)

  // STEP: write current (waits its loads via data-dep), refill reg set with
  // loads 2 ahead, one barrier, then VMEM-free compute.
#define STEP(SS, RS)                        \
  WRITE(SS, RS);                            \
  if ((SS) + 2 < 24) ISSUE((SS) + 2, RS);   \
  BARRIER;                                  \
  COMPUTE(SS)

  LOADX(0);
  ISSUE(0, rs0);
  ISSUE(1, rs1);

  STEP(0, rs0);  STEP(1, rs1);  STEP(2, rs0);  STEP(3, rs1);
  STEP(4, rs0);  STEP(5, rs1);  STEP(6, rs0);  STEP(7, rs1);
  STEP(8, rs0);  STEP(9, rs1);  STEP(10, rs0); STEP(11, rs1);
  LOADX(1);
  STEP(12, rs0); STEP(13, rs1); STEP(14, rs0); STEP(15, rs1);
  STEP(16, rs0); STEP(17, rs1); STEP(18, rs0); STEP(19, rs1);
  STEP(20, rs0); STEP(21, rs1); STEP(22, rs0); STEP(23, rs1);

#undef STEP
#undef COMPUTE
#undef WRITE
#undef ISSUE
#undef WOFF
#undef LOADX

  // LSTM activation + h write. C frag: col = c, row = kg*4 + j. acc idx = g*4+cg.
#pragma unroll
  for (int cg = 0; cg < 4; ++cg) {
#pragma unroll
    for (int j = 0; j < 4; ++j) {
      float iv = acc[cg][j];
      float gv = acc[4 + cg][j];
      float ov = acc[8 + cg][j];
      float cc = sigmoid_f(iv) * tanh_f(gv);
      float h = sigmoid_f(ov) * tanh_f(cc);
      int b = wv * 16 + kg * 4 + j;
      out[(((size_t)b * T_ + t) << 9) + d0 + cg * 16 + c] = h;
    }
  }
}

// One wave per (b,t) row of 512; in-place softmax(20*h).
__global__ __launch_bounds__(256) void softmax_kernel(float* __restrict__ io) {
  const int lane = threadIdx.x & 63;
  const int row = blockIdx.x * 4 + (threadIdx.x >> 6);
  float* p = io + ((size_t)row << 9);
  float4 v0 = *(const float4*)(p + lane * 4);
  float4 v1 = *(const float4*)(p + 256 + lane * 4);
  float l[8] = {20.f * v0.x, 20.f * v0.y, 20.f * v0.z, 20.f * v0.w,
                20.f * v1.x, 20.f * v1.y, 20.f * v1.z, 20.f * v1.w};
  float m = l[0];
#pragma unroll
  for (int j = 1; j < 8; ++j) m = fmaxf(m, l[j]);
#pragma unroll
  for (int o = 32; o > 0; o >>= 1) m = fmaxf(m, __shfl_xor(m, o, 64));
  float e[8], s = 0.f;
#pragma unroll
  for (int j = 0; j < 8; ++j) {
    e[j] = __expf(l[j] - m);
    s += e[j];
  }
#pragma unroll
  for (int o = 32; o > 0; o >>= 1) s += __shfl_xor(s, o, 64);
  float inv = 1.0f / s;
  float4 o0 = {e[0] * inv, e[1] * inv, e[2] * inv, e[3] * inv};
  float4 o1 = {e[4] * inv, e[5] * inv, e[6] * inv, e[7] * inv};
  *(float4*)(p + lane * 4) = o0;
  *(float4*)(p + 256 + lane * 4) = o1;
}

extern "C" void kernel_launch(void* const* d_in, const int* in_sizes, int n_in,
                              void* d_out, int out_size, void* d_ws, size_t ws_size,
                              hipStream_t stream) {
  const float* x = (const float*)d_in[0];
  const float* w = (const float*)d_in[1];
  float* out = (float*)d_out;
  lstm_gates_kernel<<<T_ * 8, 256, 0, stream>>>(x, w, out);
  softmax_kernel<<<(B_ * T_) / 4, 256, 0, stream>>>(out);
}